// Round 4
// baseline (14545.610 us; speedup 1.0000x reference)
//
#include <hip/hip_runtime.h>
#include <cstdint>
#include <cstddef>

typedef unsigned short u16;
typedef unsigned int u32;
typedef __attribute__((ext_vector_type(8))) short bf16x8;  // 8 bf16 (4 VGPRs) — MFMA A/B frag
typedef __attribute__((ext_vector_type(4))) float f32x4;   // MFMA C/D frag

#define T_SEQ 512
#define HID 512

// ---------- dtype helpers ----------
__device__ __forceinline__ u16 f2bf(float f) {
  union { float f; u32 i; } c; c.f = f;
  u32 r = (c.i + 0x7FFFu + ((c.i >> 16) & 1u)) >> 16;  // RNE
  return (u16)r;
}
__device__ __forceinline__ u16 f2h(float f) {
  union { _Float16 h; u16 u; } c; c.h = (_Float16)f; return c.u;
}
__device__ __forceinline__ float h2f(u16 u) {
  union { u16 u; _Float16 h; } c; c.u = u; return (float)c.h;
}
__device__ __forceinline__ float sigmf(float x) { return 1.f / (1.f + __expf(-x)); }
__device__ __forceinline__ float tanhfast(float x) {
  float e = __expf(2.f * x); return 1.f - 2.f / (e + 1.f);  // saturates to ±1
}

// ---------------------------------------------------------------------------
// xg GEMM (unchanged — passed in round 2; not the bottleneck)
// ---------------------------------------------------------------------------
template <int AF32>
__launch_bounds__(256)
__global__ void gemm_xg(const void* __restrict__ Av,
                        const float* __restrict__ W0, const float* __restrict__ W1,
                        const float* __restrict__ b0, const float* __restrict__ b1,
                        u16* __restrict__ xg0, u16* __restrict__ xg1, int K) {
  const int dir = blockIdx.z;
  const float* W = dir ? W1 : W0;
  const float* bias = dir ? b1 : b0;
  u16* xg = dir ? xg1 : xg0;
  const int bm = blockIdx.x, bn = blockIdx.y;
  const int tid = threadIdx.x, lane = tid & 63, wv = tid >> 6;
  const int wm = wv & 1, wn = wv >> 1, quad = lane >> 4, l15 = lane & 15;

  __shared__ u16 As[128 * 40];
  __shared__ u16 Bs[128 * 40];

  f32x4 acc[4][4] = {};
  const float* Wb = W + (size_t)(bn * 128) * K;

  for (int k0 = 0; k0 < K; k0 += 32) {
    __syncthreads();
    if constexpr (AF32) {
      const float* Ab = (const float*)Av + (size_t)(bm * 128) * K;
#pragma unroll
      for (int it = 0; it < 4; ++it) {
        int c = tid + it * 256;
        int row = c >> 3, kp = (c & 7) * 4;
        float4 v = *(const float4*)(Ab + (size_t)row * K + k0 + kp);
        ushort4 s = { f2bf(v.x), f2bf(v.y), f2bf(v.z), f2bf(v.w) };
        *(ushort4*)(&As[row * 40 + kp]) = s;
      }
    } else {
      const u16* Ab = (const u16*)Av + (size_t)(bm * 128) * K;
#pragma unroll
      for (int it = 0; it < 2; ++it) {
        int c = tid + it * 256;
        int row = c >> 2, kp = (c & 3) * 8;
        *(bf16x8*)(&As[row * 40 + kp]) = *(const bf16x8*)(Ab + (size_t)row * K + k0 + kp);
      }
    }
#pragma unroll
    for (int it = 0; it < 4; ++it) {
      int c = tid + it * 256;
      int row = c >> 3, kp = (c & 7) * 4;
      float4 v = *(const float4*)(Wb + (size_t)row * K + k0 + kp);
      ushort4 s = { f2bf(v.x), f2bf(v.y), f2bf(v.z), f2bf(v.w) };
      *(ushort4*)(&Bs[row * 40 + kp]) = s;
    }
    __syncthreads();
    bf16x8 af[4], bf[4];
#pragma unroll
    for (int i = 0; i < 4; ++i) {
      af[i] = *(const bf16x8*)(&As[(wm * 64 + i * 16 + l15) * 40 + quad * 8]);
      bf[i] = *(const bf16x8*)(&Bs[(wn * 64 + i * 16 + l15) * 40 + quad * 8]);
    }
#pragma unroll
    for (int mi = 0; mi < 4; ++mi)
#pragma unroll
      for (int ni = 0; ni < 4; ++ni)
        acc[mi][ni] = __builtin_amdgcn_mfma_f32_16x16x32_bf16(af[mi], bf[ni], acc[mi][ni], 0, 0, 0);
  }

#pragma unroll
  for (int ni = 0; ni < 4; ++ni) {
    int n = bn * 128 + wn * 64 + ni * 16 + l15;
    float bv = bias[n];
#pragma unroll
    for (int mi = 0; mi < 4; ++mi) {
      int m0 = bm * 128 + wm * 64 + mi * 16 + quad * 4;
#pragma unroll
      for (int r = 0; r < 4; ++r)
        xg[(size_t)(m0 + r) * 1536 + n] = f2h(acc[mi][ni][r] + bv);
    }
  }
}

// ---------------------------------------------------------------------------
// GRU recurrence, wave-autonomous (round-3 structure; only the out_f32 store
// path changed: convergent per-lane scalar stores — the round-3 failure was a
// __shfl_xor inside a divergent branch, UB for the inactive source lane).
// ---------------------------------------------------------------------------
__launch_bounds__(256, 1)
__global__ void gru_rec(const u16* __restrict__ xg_f, const u16* __restrict__ xg_b,
                        const float* __restrict__ whh_f, const float* __restrict__ whh_b,
                        const float* __restrict__ bhh_f, const float* __restrict__ bhh_b,
                        const float* __restrict__ h0_f, const float* __restrict__ h0_b,
                        void* __restrict__ outp, int out_stride, int out_f32,
                        u16* __restrict__ hbuf, int* __restrict__ flags_base, int Tn) {
  const int dir = blockIdx.y;
  const u16* xg    = dir ? xg_b  : xg_f;
  const float* whh = dir ? whh_b : whh_f;
  const float* bhh = dir ? bhh_b : bhh_f;
  const float* h0  = dir ? h0_b  : h0_f;
  const int w = blockIdx.x;                          // 0..7
  const int tid = threadIdx.x, lane = tid & 63, q = tid >> 6;  // wave 0..3
  const int quad = lane >> 4, l15 = lane & 15;
  const int j = w * 64 + q * 16 + l15;               // this lane's hidden index
  const int myflag = w * 4 + q;
  int* flags = flags_base + dir * 64;                // 32 used
  u16* hb0 = hbuf + (dir * 2 + 0) * (16 * 512);
  u16* hb1 = hbuf + (dir * 2 + 1) * (16 * 512);
  const int dir_off = dir * 512;

  // --- register-resident whh B-frags: wfr[g][kt], B[k=quad*8+jj][n=l15] ---
  bf16x8 wfr[3][16];
#pragma unroll
  for (int g = 0; g < 3; ++g) {
    const float* wp = whh + (size_t)(g * 512 + j) * 512 + quad * 8;
#pragma unroll
    for (int kt = 0; kt < 16; ++kt) {
      float4 a = *(const float4*)(wp + kt * 32);
      float4 b = *(const float4*)(wp + kt * 32 + 4);
      bf16x8 fr;
      fr[0] = (short)f2bf(a.x); fr[1] = (short)f2bf(a.y);
      fr[2] = (short)f2bf(a.z); fr[3] = (short)f2bf(a.w);
      fr[4] = (short)f2bf(b.x); fr[5] = (short)f2bf(b.y);
      fr[6] = (short)f2bf(b.z); fr[7] = (short)f2bf(b.w);
      wfr[g][kt] = fr;
    }
  }
  float bh[3];
#pragma unroll
  for (int g = 0; g < 3; ++g) bh[g] = bhh[g * 512 + j];

  // --- h0: fp32 carry regs + publish bf16 slice to hb1 (parity of "step -1") ---
  float hp4[4];
  u32 sv[4];
#pragma unroll
  for (int r = 0; r < 4; ++r) {
    int b = quad * 4 + r;
    hp4[r] = h0[b * 512 + j];
    u32 m = f2bf(hp4[r]);
    u32 nb = (u32)__shfl_xor((int)m, 1);             // convergent: all 64 lanes
    sv[r] = m | (nb << 16);
  }
  if (!(l15 & 1)) {
#pragma unroll
    for (int r = 0; r < 4; ++r)
      __hip_atomic_store((u32*)(hb1 + (quad * 4 + r) * 512 + j), sv[r],
                         __ATOMIC_RELAXED, __HIP_MEMORY_SCOPE_AGENT);
  }
  if (lane == 0)
    __hip_atomic_store(&flags[myflag], 1, __ATOMIC_RELEASE, __HIP_MEMORY_SCOPE_AGENT);

  for (int t = 0; t < Tn; ++t) {
    const int te = dir ? (Tn - 1 - t) : t;
    // (a) xg prefetch into registers (independent of h; in flight during poll)
    u16 xgv[3][4];
#pragma unroll
    for (int g = 0; g < 3; ++g)
#pragma unroll
      for (int r = 0; r < 4; ++r)
        xgv[g][r] = xg[(size_t)((quad * 4 + r) * Tn + te) * 1536 + g * 512 + j];

    // (b) poll all 32 wave-flags (acquire folded into poll loads)
    const int need = t + 1;
    int fv = __hip_atomic_load(&flags[lane & 31], __ATOMIC_ACQUIRE, __HIP_MEMORY_SCOPE_AGENT);
    while (__any(fv < need)) {
      __builtin_amdgcn_s_sleep(1);
      fv = __hip_atomic_load(&flags[lane & 31], __ATOMIC_ACQUIRE, __HIP_MEMORY_SCOPE_AGENT);
    }

    // (c) A-frags: full 16x512 bf16 h_{t-1} (post-acquire)
    const u16* hsrc = (t & 1) ? hb0 : hb1;
    const u16* hp = hsrc + l15 * 512 + quad * 8;
    bf16x8 afr[16];
#pragma unroll
    for (int kt = 0; kt < 16; ++kt) afr[kt] = *(const bf16x8*)(hp + kt * 32);

    // (d) 3 gate-tiles of MFMA, accumulators stay in this lane
    f32x4 acc[3] = {};
#pragma unroll
    for (int kt = 0; kt < 16; ++kt)
#pragma unroll
      for (int g = 0; g < 3; ++g)
        acc[g] = __builtin_amdgcn_mfma_f32_16x16x32_bf16(afr[kt], wfr[g][kt], acc[g], 0, 0, 0);

    // (e) gate math in-register; publish h_t (shfl here is convergent)
    u16* hbw = (t & 1) ? hb1 : hb0;
    float hv4[4];
#pragma unroll
    for (int r = 0; r < 4; ++r) {
      float xr = h2f(xgv[0][r]);
      float xz = h2f(xgv[1][r]);
      float xn = h2f(xgv[2][r]);
      float rg = sigmf(xr + acc[0][r] + bh[0]);
      float zg = sigmf(xz + acc[1][r] + bh[1]);
      float ng = tanhfast(xn + rg * (acc[2][r] + bh[2]));
      float hv = (1.f - zg) * ng + zg * hp4[r];
      hp4[r] = hv;
      hv4[r] = hv;
      u32 m = f2bf(hv);
      u32 nb = (u32)__shfl_xor((int)m, 1);
      sv[r] = m | (nb << 16);
    }
    if (!(l15 & 1)) {
#pragma unroll
      for (int r = 0; r < 4; ++r)
        __hip_atomic_store((u32*)(hbw + (quad * 4 + r) * 512 + j), sv[r],
                           __ATOMIC_RELAXED, __HIP_MEMORY_SCOPE_AGENT);
    }
    // (f) signal: release store drains this wave's vmcnt (h stores + afr loads)
    if (lane == 0)
      __hip_atomic_store(&flags[myflag], t + 2, __ATOMIC_RELEASE, __HIP_MEMORY_SCOPE_AGENT);

    // (g) sequence output — after the signal, off the critical path.
    // CONVERGENT stores only (round-3 bug: shfl in divergent branch).
    if (out_f32) {
#pragma unroll
      for (int r = 0; r < 4; ++r)
        ((float*)outp)[(size_t)((quad * 4 + r) * Tn + te) * out_stride + dir_off + j] = hv4[r];
    } else if (!(l15 & 1)) {
#pragma unroll
      for (int r = 0; r < 4; ++r)
        *(u32*)((u16*)outp + (size_t)((quad * 4 + r) * Tn + te) * out_stride + dir_off + j) = sv[r];
    }
  }
}

// ---------------------------------------------------------------------------
// Final FC: d_out[b] = sigmoid(out2[b, T-1, :] . fc_w + fc_b)   (all fp32)
// ---------------------------------------------------------------------------
__global__ void fc_kernel(const float* __restrict__ out2, const float* __restrict__ fc_w,
                          const float* __restrict__ fc_b, float* __restrict__ dst) {
  int b = blockIdx.x, lane = threadIdx.x;  // 64 threads
  const float* row = out2 + ((size_t)b * T_SEQ + (T_SEQ - 1)) * HID;
  float s = 0.f;
  for (int jj = lane; jj < HID; jj += 64) s += row[jj] * fc_w[jj];
#pragma unroll
  for (int off = 32; off > 0; off >>= 1) s += __shfl_down(s, off, 64);
  if (lane == 0) dst[b] = sigmf(s + fc_b[0]);
}

// ---------------------------------------------------------------------------
// inputs (fp32): 0 x, 1 h1, 2 h2, [3..6]=l0f(wih,whh,bih,bhh), [7..10]=l0b,
// [11..14]=l1f, [15..18]=l1b, [19..22]=l2f, [23..26]=l2b, [27..30]=g2, 31 fc_w, 32 fc_b
// d_out (fp32): 16 sigmoid logits, then out2 [16,512,512].
// ws: xg0 fp16 (8192*1536) | xg1 fp16 | outb bf16 (8192*1024) | hbuf bf16 (4*8192)
//     | flags (4 layers * 128 int)
// ---------------------------------------------------------------------------
extern "C" void kernel_launch(void* const* d_in, const int* in_sizes, int n_in,
                              void* d_out, int out_size, void* d_ws, size_t ws_size,
                              hipStream_t stream) {
  const float* x  = (const float*)d_in[0];
  const float* h1 = (const float*)d_in[1];
  const float* h2 = (const float*)d_in[2];
  auto P = [&](int i) { return (const float*)d_in[i]; };

  u16* xg0 = (u16*)d_ws;
  u16* xg1 = xg0 + (size_t)8192 * 1536;
  u16* outb = xg1 + (size_t)8192 * 1536;
  u16* hbuf = outb + (size_t)8192 * 1024;
  int* flags = (int*)(hbuf + 4 * 8192);
  float* out_f = (float*)d_out;
  float* out2 = out_f + 16;

  hipMemsetAsync(flags, 0, 4 * 128 * sizeof(int), stream);

  // layer 0 (A = x fp32, K=2048)
  gemm_xg<1><<<dim3(64, 12, 2), 256, 0, stream>>>(x, P(3), P(7), P(5), P(9), xg0, xg1, 2048);
  gru_rec<<<dim3(8, 2), 256, 0, stream>>>(xg0, xg1, P(4), P(8), P(6), P(10),
                                          h1, h1 + 8192, outb, 1024, 0, hbuf, flags, T_SEQ);
  // layer 1 (A = outb bf16, K=1024)
  gemm_xg<0><<<dim3(64, 12, 2), 256, 0, stream>>>(outb, P(11), P(15), P(13), P(17), xg0, xg1, 1024);
  gru_rec<<<dim3(8, 2), 256, 0, stream>>>(xg0, xg1, P(12), P(16), P(14), P(18),
                                          h1 + 2 * 8192, h1 + 3 * 8192, outb, 1024, 0, hbuf,
                                          flags + 128, T_SEQ);
  // layer 2 (K=1024)
  gemm_xg<0><<<dim3(64, 12, 2), 256, 0, stream>>>(outb, P(19), P(23), P(21), P(25), xg0, xg1, 1024);
  gru_rec<<<dim3(8, 2), 256, 0, stream>>>(xg0, xg1, P(20), P(24), P(22), P(26),
                                          h1 + 4 * 8192, h1 + 5 * 8192, outb, 1024, 0, hbuf,
                                          flags + 256, T_SEQ);
  // g2 (unidirectional, K=1024) -> writes out2 region of d_out (fp32)
  gemm_xg<0><<<dim3(64, 12, 1), 256, 0, stream>>>(outb, P(27), P(27), P(29), P(29), xg0, xg1, 1024);
  gru_rec<<<dim3(8, 1), 256, 0, stream>>>(xg0, xg0, P(28), P(28), P(30), P(30),
                                          h2, h2, out2, 512, 1, hbuf, flags + 384, T_SEQ);
  fc_kernel<<<16, 64, 0, stream>>>(out2, P(31), P(32), out_f);
}